// Round 6
// baseline (227.351 us; speedup 1.0000x reference)
//
#include <hip/hip_runtime.h>

#define NROWS 8192
#define DDIM  1024

typedef short  bf16x8 __attribute__((ext_vector_type(8)));  // 8 bf16 in 4 VGPRs
typedef float  f32x4  __attribute__((ext_vector_type(4)));
typedef unsigned short ushort_t;

// ---- round-to-nearest-even fp32 -> bf16 (bit pattern in ushort) ----
__device__ __forceinline__ ushort_t f2bf(float f) {
    union { float f; unsigned u; } v; v.f = f;
    unsigned r = v.u + 0x7fffu + ((v.u >> 16) & 1u);
    return (ushort_t)(r >> 16);
}

// async global->LDS, 16B per lane, linear LDS dest (wave-uniform base + lane*16)
#define GLD(gp, lp)                                                        \
    __builtin_amdgcn_global_load_lds(                                      \
        (const __attribute__((address_space(1))) void*)(gp),               \
        (__attribute__((address_space(3))) void*)(lp), 16, 0, 0)

// ============================================================================
// Kernel 1: row L2-normalize fp32 -> bf16. One block (256t) per row.
// Also zeroes top/bot (and out) so no separate memset dispatch is needed.
// ============================================================================
__global__ __launch_bounds__(256) void snnl_normalize(
    const float* __restrict__ x, ushort_t* __restrict__ xn,
    float* __restrict__ top, float* __restrict__ bot, float* __restrict__ out)
{
    const int row = (int)blockIdx.x;
    const int tid = (int)threadIdx.x;
    if (tid == 0) {
        top[row] = 0.0f;
        bot[row] = 0.0f;
        if (row == 0) out[0] = 0.0f;
    }
    const float4 v = ((const float4*)(x + (size_t)row * DDIM))[tid];
    float ss = v.x * v.x + v.y * v.y + v.z * v.z + v.w * v.w;
#pragma unroll
    for (int m = 32; m >= 1; m >>= 1) ss += __shfl_xor(ss, m);
    __shared__ float ws4[4];
    if ((tid & 63) == 0) ws4[tid >> 6] = ss;
    __syncthreads();
    const float tot = ws4[0] + ws4[1] + ws4[2] + ws4[3];
    const float inv = 1.0f / fmaxf(sqrtf(tot), 1e-8f);   // COS_EPS clamp
    ushort4 o;
    o.x = f2bf(v.x * inv);
    o.y = f2bf(v.y * inv);
    o.z = f2bf(v.z * inv);
    o.w = f2bf(v.w * inv);
    ((ushort4*)(xn + (size_t)row * DDIM))[tid] = o;
}

// ============================================================================
// Kernel 2: fused sim-GEMM + exp + masked row/col sums, triangle with
// MIRROR-FOLD BALANCING inside the R1-measured grid (64,16):
//   dead blocks (bx0 > 4by0+3) mirror to (63-bx0, 15-by0) and do jtl {2,3};
//   full panels (bx0 < 4by0) do jtl {0,1} (back half comes from the mirror);
//   diagonal-crossing panels do jtl [bx0-4by0, 4).
// -> every block does ~2 tiles (diag: 1-4); all 2080 upper tiles exactly once.
// Dispatch-order locality preserved: same-by blocks co-locate per XCD and
// share the B-(half)panel in L2 (R1/R5-verified FETCH ~75MB).
// LDS XOR-swizzled (byte ^= (row&7)<<4) via pre-swizzled global source
// (global_load_lds writes linearly) + swizzled ds_read -> conflict-free b128.
// ============================================================================
__global__ __launch_bounds__(256, 2) void snnl_main(
    const ushort_t* __restrict__ xn, const int* __restrict__ y,
    const float* __restrict__ T,
    float* __restrict__ top, float* __restrict__ bot)
{
    const int bx0 = (int)blockIdx.x;
    const int by0 = (int)blockIdx.y;

    int bx, by, jbeg, jend;
    if (bx0 > 4 * by0 + 3) {            // dead -> mirror, back half
        bx = 63 - bx0; by = 15 - by0; jbeg = 2; jend = 4;
    } else if (bx0 < 4 * by0) {         // full panel -> front half
        bx = bx0;      by = by0;      jbeg = 0; jend = 2;
    } else {                            // diagonal-crossing -> tail from jtl0
        bx = bx0;      by = by0;      jbeg = bx0 - 4 * by0; jend = 4;
    }

    __shared__ char smem[32768];          // A tile 16KB | B tile 16KB
    __shared__ int  yrow_s[128];
    __shared__ int  ycol_s[512];

    const int tid  = (int)threadIdx.x;
    const int lane = tid & 63;
    const int w    = tid >> 6;
    const int wr   = w >> 1;              // wave row (0..1) -> 64 output rows
    const int wc   = w & 1;               // wave col (0..1) -> 64 output cols
    const int i0   = bx * 128;
    const int j0   = by * 512;

    if (tid < 128) yrow_s[tid] = y[i0 + tid];
    ycol_s[tid]       = y[j0 + tid];
    ycol_s[tid + 256] = y[j0 + 256 + tid];
    // first K-loop __syncthreads() covers these before any use

    const float invT = 1.0f / T[0];

    // --- staging constants: thread t writes LDS bytes [q*4096 + t*16, +16) ---
    // LDS linear offset o: row = o>>7, col byte = o&127.
    // Swizzle (involution): stored col = col ^ ((row&7)<<4).
    const int  rr  = tid >> 3;                               // tile row % 32
    const int  scb = (((tid & 7) ^ (rr & 7)) << 4);          // source col byte
    const char* const xb = (const char*)xn;

    // --- fragment-read constants (read side applies the same XOR) ---
    const int c0 = (((lane >> 4) << 4)) ^ ((lane & 7) << 4);
    int arow[4], brow[4];
#pragma unroll
    for (int mi = 0; mi < 4; ++mi) arow[mi] = (wr * 64 + mi * 16 + (lane & 15)) * 128;
#pragma unroll
    for (int ni = 0; ni < 4; ++ni) brow[ni] = 16384 + (wc * 64 + ni * 16 + (lane & 15)) * 128;

    float tsum[4][4], bsum[4][4];
#pragma unroll
    for (int mi = 0; mi < 4; ++mi)
#pragma unroll
        for (int r = 0; r < 4; ++r) { tsum[mi][r] = 0.0f; bsum[mi][r] = 0.0f; }

    const f32x4 zero4 = {0.0f, 0.0f, 0.0f, 0.0f};

    for (int jtl = jbeg; jtl < jend; ++jtl) {
        const int bj = 4 * by + jtl;
        const int jb = j0 + jtl * 128;
        const bool strict = (bx < bj);              // off-diagonal tile

        f32x4 acc[4][4];
#pragma unroll
        for (int mi = 0; mi < 4; ++mi)
#pragma unroll
            for (int ni = 0; ni < 4; ++ni) acc[mi][ni] = zero4;

        for (int kt = 0; kt < 16; ++kt) {
            const size_t kb = ((size_t)kt << 7) + (size_t)scb;
#pragma unroll
            for (int q = 0; q < 4; ++q)
                GLD(xb + (((size_t)(i0 + q * 32 + rr)) << 11) + kb,
                    smem + (q << 12) + (tid << 4));
#pragma unroll
            for (int q = 0; q < 4; ++q)
                GLD(xb + (((size_t)(jb + q * 32 + rr)) << 11) + kb,
                    smem + 16384 + (q << 12) + (tid << 4));
            __syncthreads();   // compiler drains vmcnt before s_barrier

#pragma unroll
            for (int ks = 0; ks < 2; ++ks) {
                const int cks = c0 ^ (ks << 6);
                bf16x8 af[4], bfr[4];
#pragma unroll
                for (int mi = 0; mi < 4; ++mi)
                    af[mi] = *(const bf16x8*)(smem + arow[mi] + cks);
#pragma unroll
                for (int ni = 0; ni < 4; ++ni)
                    bfr[ni] = *(const bf16x8*)(smem + brow[ni] + cks);
#pragma unroll
                for (int mi = 0; mi < 4; ++mi)
#pragma unroll
                    for (int ni = 0; ni < 4; ++ni)
                        acc[mi][ni] = __builtin_amdgcn_mfma_f32_16x16x32_bf16(
                            af[mi], bfr[ni], acc[mi][ni], 0, 0, 0);
            }
            __syncthreads();
        }

        // ---- fused epilogue: f = exp((sim-1)/T), masked row AND col sums ----
        int yjv[4], jgv[4];
#pragma unroll
        for (int ni = 0; ni < 4; ++ni) {
            const int jloc = jtl * 128 + wc * 64 + ni * 16 + (lane & 15);
            yjv[ni] = ycol_s[jloc];
            jgv[ni] = j0 + jloc;
        }
        float ct[4], cb[4];                 // column accumulators (per ni)
#pragma unroll
        for (int ni = 0; ni < 4; ++ni) { ct[ni] = 0.0f; cb[ni] = 0.0f; }

#pragma unroll
        for (int mi = 0; mi < 4; ++mi) {
#pragma unroll
            for (int r = 0; r < 4; ++r) {
                const int il = wr * 64 + mi * 16 + ((lane >> 4) << 2) + r;
                const int ig = i0 + il;
                const int yi = yrow_s[il];
                float ba = 0.0f, ta = 0.0f;
#pragma unroll
                for (int ni = 0; ni < 4; ++ni) {
                    const float fv = __expf((acc[mi][ni][r] - 1.0f) * invT);
                    const bool  sm = (yi == yjv[ni]);
                    const float bv = (ig != jgv[ni]) ? fv : 0.0f;  // off-diag
                    const float tv = sm ? bv : 0.0f;               // same-label
                    ba += bv;  ta += tv;
                    cb[ni] += bv;  ct[ni] += tv;                   // mirror tile
                }
                bsum[mi][r] += ba;
                tsum[mi][r] += ta;
            }
        }

        if (strict) {
            // col reduce: col = lane&15 fixed, sum the 4 lane-quarters
#pragma unroll
            for (int ni = 0; ni < 4; ++ni) {
                float tv = ct[ni], bv = cb[ni];
                tv += __shfl_xor(tv, 16); tv += __shfl_xor(tv, 32);
                bv += __shfl_xor(bv, 16); bv += __shfl_xor(bv, 32);
                if (lane < 16) {
                    atomicAdd(&top[jgv[ni]], tv);
                    atomicAdd(&bot[jgv[ni]], bv);
                }
            }
        }
    }

    // ---- row reduce across the 16 lanes sharing a row, one atomic set ----
#pragma unroll
    for (int mi = 0; mi < 4; ++mi) {
#pragma unroll
        for (int r = 0; r < 4; ++r) {
            float t = tsum[mi][r];
            float b = bsum[mi][r];
            t += __shfl_xor(t, 1); t += __shfl_xor(t, 2);
            t += __shfl_xor(t, 4); t += __shfl_xor(t, 8);
            b += __shfl_xor(b, 1); b += __shfl_xor(b, 2);
            b += __shfl_xor(b, 4); b += __shfl_xor(b, 8);
            if ((lane & 15) == 0) {
                const int ig = i0 + wr * 64 + mi * 16 + ((lane >> 4) << 2) + r;
                atomicAdd(&top[ig], t);
                atomicAdd(&bot[ig], b);
            }
        }
    }
}

// ============================================================================
// Kernel 3: loss = -mean(log((top+1e-9)/bot)); out pre-zeroed by normalize.
// ============================================================================
__global__ __launch_bounds__(256) void snnl_loss(
    const float* __restrict__ top, const float* __restrict__ bot,
    float* __restrict__ out)
{
    const int tid = (int)threadIdx.x;
    const int i   = (int)blockIdx.x * 256 + tid;
    float s = __logf((top[i] + 1e-9f) / bot[i]);
#pragma unroll
    for (int m = 32; m >= 1; m >>= 1) s += __shfl_xor(s, m);
    __shared__ float w4[4];
    if ((tid & 63) == 0) w4[tid >> 6] = s;
    __syncthreads();
    if (tid == 0)
        atomicAdd(out, -(w4[0] + w4[1] + w4[2] + w4[3]) * (1.0f / (float)NROWS));
}

// ============================================================================
extern "C" void kernel_launch(void* const* d_in, const int* in_sizes, int n_in,
                              void* d_out, int out_size, void* d_ws, size_t ws_size,
                              hipStream_t stream)
{
    const float* x = (const float*)d_in[0];
    const int*   y = (const int*)d_in[1];
    const float* T = (const float*)d_in[2];
    float* out = (float*)d_out;

    char* ws = (char*)d_ws;
    ushort_t* xn  = (ushort_t*)ws;                              // 16 MiB bf16 Xn
    float*    top = (float*)(ws + (size_t)16 * 1024 * 1024);    // 32 KiB
    float*    bot = top + NROWS;                                // 32 KiB

    snnl_normalize<<<NROWS, 256, 0, stream>>>(x, xn, top, bot, out);
    snnl_main<<<dim3(64, 16), 256, 0, stream>>>(xn, y, T, top, bot);
    snnl_loss<<<NROWS / 256, 256, 0, stream>>>(top, bot, out);
}

// Round 7
// 180.169 us; speedup vs baseline: 1.2619x; 1.2619x over previous
//
#include <hip/hip_runtime.h>

#define NROWS 8192
#define DDIM  1024

typedef short  bf16x8 __attribute__((ext_vector_type(8)));  // 8 bf16 in 4 VGPRs
typedef float  f32x4  __attribute__((ext_vector_type(4)));
typedef unsigned short ushort_t;

// ---- round-to-nearest-even fp32 -> bf16 (bit pattern in ushort) ----
__device__ __forceinline__ ushort_t f2bf(float f) {
    union { float f; unsigned u; } v; v.f = f;
    unsigned r = v.u + 0x7fffu + ((v.u >> 16) & 1u);
    return (ushort_t)(r >> 16);
}

// async global->LDS, 16B per lane, linear LDS dest (wave-uniform base + lane*16)
#define GLD(gp, lp)                                                        \
    __builtin_amdgcn_global_load_lds(                                      \
        (const __attribute__((address_space(1))) void*)(gp),               \
        (__attribute__((address_space(3))) void*)(lp), 16, 0, 0)

// ============================================================================
// Kernel 1: row L2-normalize fp32 -> bf16. One block (256t) per row.
// Also zeroes top/bot (and out) so no separate memset dispatch is needed.
// ============================================================================
__global__ __launch_bounds__(256) void snnl_normalize(
    const float* __restrict__ x, ushort_t* __restrict__ xn,
    float* __restrict__ top, float* __restrict__ bot, float* __restrict__ out)
{
    const int row = (int)blockIdx.x;
    const int tid = (int)threadIdx.x;
    if (tid == 0) {
        top[row] = 0.0f;
        bot[row] = 0.0f;
        if (row == 0) out[0] = 0.0f;
    }
    const float4 v = ((const float4*)(x + (size_t)row * DDIM))[tid];
    float ss = v.x * v.x + v.y * v.y + v.z * v.z + v.w * v.w;
#pragma unroll
    for (int m = 32; m >= 1; m >>= 1) ss += __shfl_xor(ss, m);
    __shared__ float ws4[4];
    if ((tid & 63) == 0) ws4[tid >> 6] = ss;
    __syncthreads();
    const float tot = ws4[0] + ws4[1] + ws4[2] + ws4[3];
    const float inv = 1.0f / fmaxf(sqrtf(tot), 1e-8f);   // COS_EPS clamp
    ushort4 o;
    o.x = f2bf(v.x * inv);
    o.y = f2bf(v.y * inv);
    o.z = f2bf(v.z * inv);
    o.w = f2bf(v.w * inv);
    ((ushort4*)(xn + (size_t)row * DDIM))[tid] = o;
}

// ============================================================================
// Kernel 2: fused sim-GEMM + exp + masked row/col sums, upper triangle, with
// XCD-COHERENT SUPERBLOCK SCHEDULING:
//   - one 128x128 tile per block, grid = 2080 (all upper-triangle tiles)
//   - xcd = bid%8 (round-robin dispatch heuristic); XCD x owns the exact
//     tile interval [x*260, (x+1)*260) of a global order laid out as
//     superblocks of 8x8 tiles (4MB A+B footprint = one XCD L2), q-major.
//   => all ~64-128 resident blocks of an XCD march in phase through one
//      superblock's 4MB working set -> staging stays L2-hit (the R4/R5/R6
//      lesson: this kernel is staging-latency-bound; footprint+synchrony
//      decide per-tile time).
//   - off-diag tiles (bi<bj) also emit transposed col-sums (sim symmetric,
//     bit-exact: same products, same k-order).
// LDS XOR-swizzled (byte ^= (row&7)<<4) via pre-swizzled global source
// (global_load_lds writes linearly) + swizzled ds_read -> conflict-free b128.
// ============================================================================
__global__ __launch_bounds__(256, 4) void snnl_main(
    const ushort_t* __restrict__ xn, const int* __restrict__ y,
    const float* __restrict__ T,
    float* __restrict__ top, float* __restrict__ bot)
{
    // ---- tile index from XCD-coherent global order ----
    const int bid = (int)blockIdx.x;
    int rem = (bid & 7) * 260 + (bid >> 3);      // global tile index
    int p = 0, q = 0;
    {
        bool done = false;
        for (int qq = 0; qq < 8 && !done; ++qq) {
            for (int pp = 0; pp <= qq; ++pp) {
                const int c = (pp == qq) ? 36 : 64;
                if (rem < c) { p = pp; q = qq; done = true; break; }
                rem -= c;
            }
        }
    }
    int ti, tj;
    if (p == q) {                                // diag superblock: tri enum
        int t = rem; tj = 7;
        for (int cc = 0; cc < 8; ++cc) {
            if (t <= cc) { tj = cc; break; }
            t -= (cc + 1);
        }
        ti = t;
    } else {                                     // full superblock
        ti = rem & 7; tj = rem >> 3;
    }
    const int bi = p * 8 + ti;
    const int bj = q * 8 + tj;
    const bool strict = (bi < bj);               // off-diagonal tile

    __shared__ char smem[32768];                 // A tile 16KB | B tile 16KB
    __shared__ int  yrow_s[128];
    __shared__ int  ycol_s[128];

    const int tid  = (int)threadIdx.x;
    const int lane = tid & 63;
    const int w    = tid >> 6;
    const int wr   = w >> 1;              // wave row (0..1) -> 64 output rows
    const int wc   = w & 1;               // wave col (0..1) -> 64 output cols
    const int i0   = bi * 128;
    const int j0   = bj * 128;

    if (tid < 128) yrow_s[tid] = y[i0 + tid];
    else           ycol_s[tid - 128] = y[j0 + tid - 128];
    // first K-loop __syncthreads() covers these before any use

    const float invT = 1.0f / T[0];

    // --- staging constants: thread t writes LDS bytes [q*4096 + t*16, +16) ---
    // LDS linear offset o: row = o>>7, col byte = o&127.
    // Swizzle (involution): stored col = col ^ ((row&7)<<4).
    const int  rr  = tid >> 3;                               // tile row % 32
    const int  scb = (((tid & 7) ^ (rr & 7)) << 4);          // source col byte
    const char* const xb = (const char*)xn;

    // --- fragment-read constants (read side applies the same XOR) ---
    const int c0 = (((lane >> 4) << 4)) ^ ((lane & 7) << 4);
    int arow[4], brow[4];
#pragma unroll
    for (int mi = 0; mi < 4; ++mi) arow[mi] = (wr * 64 + mi * 16 + (lane & 15)) * 128;
#pragma unroll
    for (int ni = 0; ni < 4; ++ni) brow[ni] = 16384 + (wc * 64 + ni * 16 + (lane & 15)) * 128;

    const f32x4 zero4 = {0.0f, 0.0f, 0.0f, 0.0f};
    f32x4 acc[4][4];
#pragma unroll
    for (int mi = 0; mi < 4; ++mi)
#pragma unroll
        for (int ni = 0; ni < 4; ++ni) acc[mi][ni] = zero4;

    for (int kt = 0; kt < 16; ++kt) {
        const size_t kb = ((size_t)kt << 7) + (size_t)scb;
#pragma unroll
        for (int qq = 0; qq < 4; ++qq)
            GLD(xb + (((size_t)(i0 + qq * 32 + rr)) << 11) + kb,
                smem + (qq << 12) + (tid << 4));
#pragma unroll
        for (int qq = 0; qq < 4; ++qq)
            GLD(xb + (((size_t)(j0 + qq * 32 + rr)) << 11) + kb,
                smem + 16384 + (qq << 12) + (tid << 4));
        __syncthreads();   // compiler drains vmcnt before s_barrier

#pragma unroll
        for (int ks = 0; ks < 2; ++ks) {
            const int cks = c0 ^ (ks << 6);
            bf16x8 af[4], bfr[4];
#pragma unroll
            for (int mi = 0; mi < 4; ++mi)
                af[mi] = *(const bf16x8*)(smem + arow[mi] + cks);
#pragma unroll
            for (int ni = 0; ni < 4; ++ni)
                bfr[ni] = *(const bf16x8*)(smem + brow[ni] + cks);
#pragma unroll
            for (int mi = 0; mi < 4; ++mi)
#pragma unroll
                for (int ni = 0; ni < 4; ++ni)
                    acc[mi][ni] = __builtin_amdgcn_mfma_f32_16x16x32_bf16(
                        af[mi], bfr[ni], acc[mi][ni], 0, 0, 0);
        }
        __syncthreads();
    }

    // ---- fused epilogue: f = exp((sim-1)/T), masked row AND col sums ----
    int yjv[4], jgv[4];
#pragma unroll
    for (int ni = 0; ni < 4; ++ni) {
        const int jloc = wc * 64 + ni * 16 + (lane & 15);
        yjv[ni] = ycol_s[jloc];
        jgv[ni] = j0 + jloc;
    }
    float ct[4], cb[4];                 // column accumulators (per ni)
#pragma unroll
    for (int ni = 0; ni < 4; ++ni) { ct[ni] = 0.0f; cb[ni] = 0.0f; }

#pragma unroll
    for (int mi = 0; mi < 4; ++mi) {
#pragma unroll
        for (int r = 0; r < 4; ++r) {
            const int il = wr * 64 + mi * 16 + ((lane >> 4) << 2) + r;
            const int ig = i0 + il;
            const int yi = yrow_s[il];
            float ba = 0.0f, ta = 0.0f;
#pragma unroll
            for (int ni = 0; ni < 4; ++ni) {
                const float fv = __expf((acc[mi][ni][r] - 1.0f) * invT);
                const bool  sm = (yi == yjv[ni]);
                const float bv = (ig != jgv[ni]) ? fv : 0.0f;  // off-diag mask
                const float tv = sm ? bv : 0.0f;               // same-label
                ba += bv;  ta += tv;
                cb[ni] += bv;  ct[ni] += tv;                   // mirror tile
            }
            // row reduce across the 16 lanes sharing this row, one atomic
            ta += __shfl_xor(ta, 1); ta += __shfl_xor(ta, 2);
            ta += __shfl_xor(ta, 4); ta += __shfl_xor(ta, 8);
            ba += __shfl_xor(ba, 1); ba += __shfl_xor(ba, 2);
            ba += __shfl_xor(ba, 4); ba += __shfl_xor(ba, 8);
            if ((lane & 15) == 0) {
                atomicAdd(&top[ig], ta);
                atomicAdd(&bot[ig], ba);
            }
        }
    }

    if (strict) {
        // col reduce: col = lane&15 fixed, sum the 4 lane-quarters
#pragma unroll
        for (int ni = 0; ni < 4; ++ni) {
            float tv = ct[ni], bv = cb[ni];
            tv += __shfl_xor(tv, 16); tv += __shfl_xor(tv, 32);
            bv += __shfl_xor(bv, 16); bv += __shfl_xor(bv, 32);
            if (lane < 16) {
                atomicAdd(&top[jgv[ni]], tv);
                atomicAdd(&bot[jgv[ni]], bv);
            }
        }
    }
}

// ============================================================================
// Kernel 3: loss = -mean(log((top+1e-9)/bot)); out pre-zeroed by normalize.
// ============================================================================
__global__ __launch_bounds__(256) void snnl_loss(
    const float* __restrict__ top, const float* __restrict__ bot,
    float* __restrict__ out)
{
    const int tid = (int)threadIdx.x;
    const int i   = (int)blockIdx.x * 256 + tid;
    float s = __logf((top[i] + 1e-9f) / bot[i]);
#pragma unroll
    for (int m = 32; m >= 1; m >>= 1) s += __shfl_xor(s, m);
    __shared__ float w4[4];
    if ((tid & 63) == 0) w4[tid >> 6] = s;
    __syncthreads();
    if (tid == 0)
        atomicAdd(out, -(w4[0] + w4[1] + w4[2] + w4[3]) * (1.0f / (float)NROWS));
}

// ============================================================================
extern "C" void kernel_launch(void* const* d_in, const int* in_sizes, int n_in,
                              void* d_out, int out_size, void* d_ws, size_t ws_size,
                              hipStream_t stream)
{
    const float* x = (const float*)d_in[0];
    const int*   y = (const int*)d_in[1];
    const float* T = (const float*)d_in[2];
    float* out = (float*)d_out;

    char* ws = (char*)d_ws;
    ushort_t* xn  = (ushort_t*)ws;                              // 16 MiB bf16 Xn
    float*    top = (float*)(ws + (size_t)16 * 1024 * 1024);    // 32 KiB
    float*    bot = top + NROWS;                                // 32 KiB

    snnl_normalize<<<NROWS, 256, 0, stream>>>(x, xn, top, bot, out);
    snnl_main<<<2080, 256, 0, stream>>>(xn, y, T, top, bot);
    snnl_loss<<<NROWS / 256, 256, 0, stream>>>(top, bot, out);
}